// Round 10
// baseline (173.171 us; speedup 1.0000x reference)
//
#include <hip/hip_runtime.h>
#include <hip/hip_bf16.h>

typedef __attribute__((ext_vector_type(4))) float f32x4;
typedef __attribute__((ext_vector_type(8))) short short8;
typedef __attribute__((ext_vector_type(4))) _Float16 f16x4;

__device__ __forceinline__ short f2bf(float f) {
    unsigned u = __builtin_bit_cast(unsigned, f);
    u += 0x7fffu + ((u >> 16) & 1u);           // RNE to bf16
    return (short)(unsigned short)(u >> 16);
}

// Pre-kernel: W -> bf16 B-fragment layout (16x16x32 MFMA) + wa = W @ a (fp32 exact)
__global__ void gat_pre(const float* __restrict__ W, const float* __restrict__ a_src,
                        const float* __restrict__ a_dst, unsigned short* __restrict__ wt,
                        float* __restrict__ wa) {
    int blk = blockIdx.x, t = threadIdx.x;
    if (blk < 8) {
        int e = blk * 256 + t;              // e = (kk*8+ct)*64 + lane
        int kk = e >> 9, ct = (e >> 6) & 7, lane = e & 63;
        int lq = lane >> 4, l15 = lane & 15;
        short8 v;
#pragma unroll
        for (int jj = 0; jj < 8; ++jj)
            v[jj] = f2bf(W[(kk * 32 + lq * 8 + jj) * 128 + ct * 16 + l15]);
        *(short8*)(wt + (size_t)e * 8) = v;
    } else if (t < 128) {
        float s1 = 0.f, s2 = 0.f;
        for (int o = 0; o < 128; ++o) {
            float w = W[t * 128 + o];
            s1 += w * a_src[o];
            s2 += w * a_dst[o];
        }
        wa[t] = s1; wa[128 + t] = s2;
    }
}

__device__ __forceinline__ void dma16(const void* g, void* l) {
    __builtin_amdgcn_global_load_lds((const __attribute__((address_space(1))) void*)g,
                                     (__attribute__((address_space(3))) void*)l, 16, 0, 0);
}

// 128 threads (2 waves). Per wave: LDS x double-buffer filled by global_load_lds
// (zero-VGPR prefetch the compiler cannot sink), counted-vmcnt pipeline.
// ONLY 16B DMAs (12B lane-stride semantics unverified -> R9's corruption suspect).
__global__ __launch_bounds__(128, 2) void gat_main(
    const float* __restrict__ x, const int* __restrict__ adj,
    const unsigned short* __restrict__ wfrag, const float* __restrict__ wa,
    float* __restrict__ out, int B)
{
    __shared__ __align__(16) unsigned short wlds[16384];   // 32 KB W fragments
    __shared__ __align__(16) float walds[256];             // 1 KB wa
    __shared__ __align__(16) float xstg[4 * 1920 + 128];   // 2 waves x 2 x-buffers + pad

    const int t = threadIdx.x;
    const int wv = t >> 6;
    const int lane = t & 63;
    const int lq = lane >> 4, l15 = lane & 15;

    // one-time W + wa fill (128 threads)
#pragma unroll
    for (int i = 0; i < 16; ++i)
        *(float4*)((char*)wlds + (t + 128 * i) * 16) =
            *(const float4*)((const char*)wfrag + (t + 128 * i) * 16);
    if (t < 64) *(float4*)(walds + t * 4) = *(const float4*)(wa + t * 4);

    const int wid = blockIdx.x * 2 + wv;
    const int wstride = gridDim.x * 2;
    const int niter = B / wstride;          // 8 for B=32768, grid=2048

    // Per-lane pre-swizzled DMA source offsets (bytes).
    // LDS 16B-chunk C holds global chunk (C&31) ^ ((C>>5)&7) of row C>>5.
    // Calls 0..6: C = k*64 + lane (rows 2k, 2k+1). Call 7: C = 416 + lane
    // (lanes 0..31 re-write row 13 idempotently, lanes 32..63 deliver row 14).
    int off16[8];
#pragma unroll
    for (int k = 0; k < 8; ++k) {
        int row = (k < 7) ? (2 * k + (lane >> 5)) : (13 + (lane >> 5));
        int cs = (lane & 31) ^ (row & 7);
        off16[k] = row * 512 + cs * 16;
    }

    float* const buf0 = xstg + (size_t)(wv * 2) * 1920;
    float* const buf1 = xstg + (size_t)(wv * 2 + 1) * 1920;
    const int xswz = (l15 < 15) ? (l15 & 7) : 0;

    __syncthreads();   // W/wa ready; waves independent afterwards

    // ---- prologue: stage batch `wid` into buf0 (+ adj bits)
    {
        const char* xb = (const char*)(x + (size_t)wid * 1920);
#pragma unroll
        for (int k = 0; k < 8; ++k)
            dma16(xb + off16[k], (char*)buf0 + ((k < 7) ? k * 1024 : 6656));
    }
    int a4c;
    {
        const volatile int* ab = (const volatile int*)(adj + (size_t)wid * 225 + l15 * 15 + lq * 4);
        int v0 = (l15 < 15) ? ab[0] : 0;
        int v1 = (l15 < 15) ? ab[1] : 0;
        int v2 = (l15 < 15) ? ab[2] : 0;
        int v3 = (l15 < 15 && lq < 3) ? ab[3] : 0;
        a4c = (v0 ? 1 : 0) | (v1 ? 2 : 0) | (v2 ? 4 : 0) | (v3 ? 8 : 0);
    }

    const f32x4 z4 = {0.f, 0.f, 0.f, 0.f};

    auto body = [&](int b, float* bcur, int a4) {
        // ---- prep: x from LDS (swizzled), zero pad row, s-partials + bf16 A-frags
        f32x4 a[8];
#pragma unroll
        for (int kk = 0; kk < 4; ++kk) {
            int c0 = kk * 8 + lq * 2;
            a[2 * kk]     = *(const f32x4*)((const char*)bcur + l15 * 512 + ((c0)     ^ xswz) * 16);
            a[2 * kk + 1] = *(const f32x4*)((const char*)bcur + l15 * 512 + ((c0 + 1) ^ xswz) * 16);
        }
        const bool vrow = (l15 < 15);
#pragma unroll
        for (int u = 0; u < 8; ++u) a[u] = vrow ? a[u] : z4;   // select, NaN-safe

        float ps = 0.f, pd = 0.f;
        short8 af[4];
#pragma unroll
        for (int kk = 0; kk < 4; ++kk) {
            f32x4 a0 = a[2 * kk], a1 = a[2 * kk + 1];
            const float* wb = walds + kk * 32 + lq * 8;
            f32x4 s0 = *(const f32x4*)(wb);
            f32x4 s1 = *(const f32x4*)(wb + 4);
            f32x4 d0 = *(const f32x4*)(wb + 128);
            f32x4 d1 = *(const f32x4*)(wb + 132);
            ps += a0.x * s0.x + a0.y * s0.y + a0.z * s0.z + a0.w * s0.w
                + a1.x * s1.x + a1.y * s1.y + a1.z * s1.z + a1.w * s1.w;
            pd += a0.x * d0.x + a0.y * d0.y + a0.z * d0.z + a0.w * d0.w
                + a1.x * d1.x + a1.y * d1.y + a1.z * d1.z + a1.w * d1.w;
            union { unsigned u[4]; short8 s8; } cv;
            asm("v_cvt_pk_bf16_f32 %0, %1, %2" : "=v"(cv.u[0]) : "v"(a0.x), "v"(a0.y));
            asm("v_cvt_pk_bf16_f32 %0, %1, %2" : "=v"(cv.u[1]) : "v"(a0.z), "v"(a0.w));
            asm("v_cvt_pk_bf16_f32 %0, %1, %2" : "=v"(cv.u[2]) : "v"(a1.x), "v"(a1.y));
            asm("v_cvt_pk_bf16_f32 %0, %1, %2" : "=v"(cv.u[3]) : "v"(a1.z), "v"(a1.w));
            af[kk] = cv.s8;
        }

        // reduce s over the 4 lq-lanes
        float ss = ps + __shfl_xor(ps, 16);
        ss += __shfl_xor(ss, 32);
        float sd = pd + __shfl_xor(pd, 16);
        sd += __shfl_xor(sd, 32);

        // h = x @ W : 32 MFMA
        f32x4 acc[8];
#pragma unroll
        for (int ct = 0; ct < 8; ++ct) acc[ct] = z4;
#pragma unroll
        for (int kk = 0; kk < 4; ++kk) {
#pragma unroll
            for (int ct = 0; ct < 8; ++ct) {
                short8 bf = *(const short8*)(wlds + ((size_t)(kk * 8 + ct) * 64 + lane) * 8);
                acc[ct] = __builtin_amdgcn_mfma_f32_16x16x32_bf16(af[kk], bf, acc[ct], 0, 0, 0);
            }
        }

        // softmax over i (axis=1), max-free; masked -> 1e-26; pad row -> 0
        float attv[4];
#pragma unroll
        for (int r = 0; r < 4; ++r) {
            float sdj = __shfl(sd, lq * 4 + r);
            float e = ss + sdj;
            e = e > 0.f ? e : 0.2f * e;
            e = fminf(e, 30.f);
            float pexp = ((a4 >> r) & 1) ? __expf(e) : 1e-26f;
            if (l15 == 15) pexp = 0.f;
            float sm = pexp;
            sm += __shfl_xor(sm, 1);
            sm += __shfl_xor(sm, 2);
            sm += __shfl_xor(sm, 4);
            sm += __shfl_xor(sm, 8);
            attv[r] = pexp * __builtin_amdgcn_rcpf(sm);
        }

        // PV operand-swapped: D = h^T @ att^T -> lane = row i=l15, float4 per ct
        f16x4 attf;
        attf[0] = (_Float16)attv[0]; attf[1] = (_Float16)attv[1];
        attf[2] = (_Float16)attv[2]; attf[3] = (_Float16)attv[3];
        f32x4 dq[8];
#pragma unroll
        for (int ct = 0; ct < 8; ++ct) {
            f16x4 hA;
            hA[0] = (_Float16)acc[ct][0]; hA[1] = (_Float16)acc[ct][1];
            hA[2] = (_Float16)acc[ct][2]; hA[3] = (_Float16)acc[ct][3];
            f32x4 o4 = __builtin_amdgcn_mfma_f32_16x16x16f16(hA, attf, z4, 0, 0, 0);
#pragma unroll
            for (int r = 0; r < 4; ++r) {
                float u = o4[r];
                o4[r] = u > 0.f ? u : (__expf(u) - 1.f);   // elu
            }
            dq[ct] = o4;
        }

        // epilogue: stage rows in the DEAD x-buffer, emit flat full-line 1KB stores
        float* const wbuf = bcur;                      // x consumed, reuse as scratch
        const int fswW = ((l15 & 1) << 2) | (l15 & 2);
        float* const obase = out + (size_t)b * 1920;
#pragma unroll
        for (int p = 0; p < 2; ++p) {
            if ((l15 >> 3) == p) {
#pragma unroll
                for (int ct = 0; ct < 8; ++ct) {
                    int qs = (ct * 4 + lq) ^ fswW;
                    *(f32x4*)(wbuf + (l15 & 7) * 132 + qs * 4) = dq[ct];
                }
            }
            asm volatile("s_waitcnt lgkmcnt(0)" ::: "memory");
#pragma unroll
            for (int it = 0; it < 4; ++it) {
                int Q = p * 256 + it * 64 + lane;
                if (Q < 480) {
                    int orr = Q >> 5;
                    int qs = (Q & 31) ^ (((orr & 1) << 2) | (orr & 2));
                    f32x4 val = *(const f32x4*)(wbuf + (orr & 7) * 132 + qs * 4);
                    *(f32x4*)(obase + (size_t)Q * 4) = val;
                }
            }
            asm volatile("" ::: "memory");
        }
    };

    // ---- main loop: iter i computes batch b, prefetches b+stride
    int cur = 0;
    for (int i = 0; i + 1 < niter; ++i) {
        const int b = wid + i * wstride;
        const int bn = b + wstride;
        float* bcur = cur ? buf1 : buf0;
        float* bnxt = cur ? buf0 : buf1;

        // adj first (drained side), then the 8 DMAs (kept-in-flight side)
        int a4n;
        {
            const volatile int* ab = (const volatile int*)(adj + (size_t)bn * 225 + l15 * 15 + lq * 4);
            int v0 = (l15 < 15) ? ab[0] : 0;
            int v1 = (l15 < 15) ? ab[1] : 0;
            int v2 = (l15 < 15) ? ab[2] : 0;
            int v3 = (l15 < 15 && lq < 3) ? ab[3] : 0;
            a4n = (v0 ? 1 : 0) | (v1 ? 2 : 0) | (v2 ? 4 : 0) | (v3 ? 8 : 0);
        }
        {
            const char* xb = (const char*)(x + (size_t)bn * 1920);
#pragma unroll
            for (int k = 0; k < 8; ++k)
                dma16(xb + off16[k], (char*)bnxt + ((k < 7) ? k * 1024 : 6656));
        }

        // Robust wait: drain everything older than the 8 newest ops (= the DMAs
        // just issued). Guarantees current batch's DMAs landed regardless of how
        // many instructions the adj loads compiled to.
        asm volatile("s_waitcnt vmcnt(8)" ::: "memory");
        __builtin_amdgcn_sched_barrier(0);

        body(b, bcur, a4c);
        a4c = a4n;
        cur ^= 1;
    }
    // tail iteration: nothing to prefetch
    asm volatile("s_waitcnt vmcnt(0)" ::: "memory");
    __builtin_amdgcn_sched_barrier(0);
    body(wid + (niter - 1) * wstride, cur ? buf1 : buf0, a4c);
}

extern "C" void kernel_launch(void* const* d_in, const int* in_sizes, int n_in,
                              void* d_out, int out_size, void* d_ws, size_t ws_size,
                              hipStream_t stream) {
    const float* x     = (const float*)d_in[0];
    const int*   adj   = (const int*)d_in[1];
    const float* W     = (const float*)d_in[2];
    const float* a_src = (const float*)d_in[3];
    const float* a_dst = (const float*)d_in[4];
    float* out = (float*)d_out;

    unsigned short* wt = (unsigned short*)d_ws;
    float* wa = (float*)((char*)d_ws + 32768);

    int B = in_sizes[0] / (15 * 128);
    int nblk = B / 16;                          // 2048: 2 waves x 8 iters each

    gat_pre<<<9, 256, 0, stream>>>(W, a_src, a_dst, wt, wa);
    gat_main<<<nblk, 128, 0, stream>>>(x, adj, wt, wa, out, B);
}

// Round 11
// 138.365 us; speedup vs baseline: 1.2516x; 1.2516x over previous
//
#include <hip/hip_runtime.h>
#include <hip/hip_bf16.h>

typedef __attribute__((ext_vector_type(4))) float f32x4;
typedef __attribute__((ext_vector_type(8))) short short8;
typedef __attribute__((ext_vector_type(4))) _Float16 f16x4;

__device__ __forceinline__ short f2bf(float f) {
    unsigned u = __builtin_bit_cast(unsigned, f);
    u += 0x7fffu + ((u >> 16) & 1u);           // RNE to bf16
    return (short)(unsigned short)(u >> 16);
}

// Pre-kernel: W -> bf16 B-fragment layout (16x16x32 MFMA) + wa = W @ a (fp32 exact)
__global__ void gat_pre(const float* __restrict__ W, const float* __restrict__ a_src,
                        const float* __restrict__ a_dst, unsigned short* __restrict__ wt,
                        float* __restrict__ wa) {
    int blk = blockIdx.x, t = threadIdx.x;
    if (blk < 8) {
        int e = blk * 256 + t;              // e = (kk*8+ct)*64 + lane
        int kk = e >> 9, ct = (e >> 6) & 7, lane = e & 63;
        int lq = lane >> 4, l15 = lane & 15;
        short8 v;
#pragma unroll
        for (int jj = 0; jj < 8; ++jj)
            v[jj] = f2bf(W[(kk * 32 + lq * 8 + jj) * 128 + ct * 16 + l15]);
        *(short8*)(wt + (size_t)e * 8) = v;
    } else if (t < 128) {
        float s1 = 0.f, s2 = 0.f;
        for (int o = 0; o < 128; ++o) {
            float w = W[t * 128 + o];
            s1 += w * a_src[o];
            s2 += w * a_dst[o];
        }
        wa[t] = s1; wa[128 + t] = s2;
    }
}

// 256 threads / 4 waves, 1 batch per wave-iter. LDS = W(32K) + wa(1K) ONLY ->
// 4 blocks/CU x 4 waves = 16 waves/CU (TLP is the binding resource; R7=12 waves
// gave 117us, R10=4 waves gave 173us). Epilogue: direct burst stores — swapped-PV
// output is row-major per lane; consecutive ct stores pair up to cover each 128B
// line back-to-back (no LDS staging, no lgkmcnt fences).
__global__ __launch_bounds__(256, 4) void gat_main(
    const float* __restrict__ x, const int* __restrict__ adj,
    const unsigned short* __restrict__ wfrag, const float* __restrict__ wa,
    float* __restrict__ out, int B)
{
    __shared__ __align__(16) unsigned short wlds[16384];   // 32 KB W fragments
    __shared__ __align__(16) float walds[256];             // 1 KB wa

    const int t = threadIdx.x;
    const int wv = t >> 6;
    const int lane = t & 63;
    const int lq = lane >> 4, l15 = lane & 15;

#pragma unroll
    for (int i = 0; i < 8; ++i)
        *(float4*)((char*)wlds + (t + 256 * i) * 16) =
            *(const float4*)((const char*)wfrag + (t + 256 * i) * 16);
    if (t < 64) *(float4*)(walds + t * 4) = *(const float4*)(wa + t * 4);
    __syncthreads();   // only barrier; waves independent afterwards

    const int wid = blockIdx.x * 4 + wv;
    const int wstride = gridDim.x * 4;
    const f32x4 z4 = {0.f, 0.f, 0.f, 0.f};
    const bool vrow = (l15 < 15);

    for (int b = wid; b < B; b += wstride) {
        // ---- load x -> regs (predicated; lane-group 15 zeroed), adj -> bitmask
        f32x4 a[8];
        {
            const float* xb = x + (size_t)b * 1920 + l15 * 128 + lq * 8;
#pragma unroll
            for (int kk = 0; kk < 4; ++kk) {
                a[2 * kk]     = vrow ? *(const f32x4*)(xb + kk * 32)     : z4;
                a[2 * kk + 1] = vrow ? *(const f32x4*)(xb + kk * 32 + 4) : z4;
            }
        }
        int a4;
        {
            const int* ab = adj + (size_t)b * 225 + l15 * 15 + lq * 4;
            int v0 = vrow ? ab[0] : 0;
            int v1 = vrow ? ab[1] : 0;
            int v2 = vrow ? ab[2] : 0;
            int v3 = (vrow && lq < 3) ? ab[3] : 0;
            a4 = (v0 ? 1 : 0) | (v1 ? 2 : 0) | (v2 ? 4 : 0) | (v3 ? 8 : 0);
        }

        // ---- prep: exact-fp32 s partials + bf16 A-fragments (cvt_pk)
        float ps = 0.f, pd = 0.f;
        short8 af[4];
#pragma unroll
        for (int kk = 0; kk < 4; ++kk) {
            f32x4 a0 = a[2 * kk], a1 = a[2 * kk + 1];
            const float* wb = walds + kk * 32 + lq * 8;
            f32x4 s0 = *(const f32x4*)(wb);
            f32x4 s1 = *(const f32x4*)(wb + 4);
            f32x4 d0 = *(const f32x4*)(wb + 128);
            f32x4 d1 = *(const f32x4*)(wb + 132);
            ps += a0.x * s0.x + a0.y * s0.y + a0.z * s0.z + a0.w * s0.w
                + a1.x * s1.x + a1.y * s1.y + a1.z * s1.z + a1.w * s1.w;
            pd += a0.x * d0.x + a0.y * d0.y + a0.z * d0.z + a0.w * d0.w
                + a1.x * d1.x + a1.y * d1.y + a1.z * d1.z + a1.w * d1.w;
            union { unsigned u[4]; short8 s8; } cv;
            asm("v_cvt_pk_bf16_f32 %0, %1, %2" : "=v"(cv.u[0]) : "v"(a0.x), "v"(a0.y));
            asm("v_cvt_pk_bf16_f32 %0, %1, %2" : "=v"(cv.u[1]) : "v"(a0.z), "v"(a0.w));
            asm("v_cvt_pk_bf16_f32 %0, %1, %2" : "=v"(cv.u[2]) : "v"(a1.x), "v"(a1.y));
            asm("v_cvt_pk_bf16_f32 %0, %1, %2" : "=v"(cv.u[3]) : "v"(a1.z), "v"(a1.w));
            af[kk] = cv.s8;
        }

        // reduce s over the 4 lq-lanes: every lane gets ss[i=l15], sd[i=l15]
        float ss = ps + __shfl_xor(ps, 16);
        ss += __shfl_xor(ss, 32);
        float sd = pd + __shfl_xor(pd, 16);
        sd += __shfl_xor(sd, 32);

        // ---- h = x @ W : 32 MFMA, W B-fragments from LDS
        f32x4 acc[8];
#pragma unroll
        for (int ct = 0; ct < 8; ++ct) acc[ct] = z4;
#pragma unroll
        for (int kk = 0; kk < 4; ++kk) {
#pragma unroll
            for (int ct = 0; ct < 8; ++ct) {
                short8 bf = *(const short8*)(wlds + ((size_t)(kk * 8 + ct) * 64 + lane) * 8);
                acc[ct] = __builtin_amdgcn_mfma_f32_16x16x32_bf16(af[kk], bf, acc[ct], 0, 0, 0);
            }
        }

        // ---- softmax over i (axis=1), max-free; masked -> 1e-26; pad row -> 0
        float attv[4];
#pragma unroll
        for (int r = 0; r < 4; ++r) {
            float sdj = __shfl(sd, lq * 4 + r);
            float e = ss + sdj;
            e = e > 0.f ? e : 0.2f * e;             // leaky relu BEFORE mask (matches ref)
            e = fminf(e, 30.f);                     // paranoia clamp
            float pexp = ((a4 >> r) & 1) ? __expf(e) : 1e-26f;
            if (l15 == 15) pexp = 0.f;              // pad row contributes nothing
            float sm = pexp;
            sm += __shfl_xor(sm, 1);
            sm += __shfl_xor(sm, 2);
            sm += __shfl_xor(sm, 4);
            sm += __shfl_xor(sm, 8);
            attv[r] = pexp * __builtin_amdgcn_rcpf(sm);
        }

        // ---- PV operand-swapped: D = h^T (A) @ att^T (B) -> lane = row i=l15,
        // cols o = ct*16 + lq*4 + r == a ready float4 per ct.
        f16x4 attf;
        attf[0] = (_Float16)attv[0]; attf[1] = (_Float16)attv[1];
        attf[2] = (_Float16)attv[2]; attf[3] = (_Float16)attv[3];
        f32x4 dq[8];
#pragma unroll
        for (int ct = 0; ct < 8; ++ct) {
            f16x4 hA;
            hA[0] = (_Float16)acc[ct][0]; hA[1] = (_Float16)acc[ct][1];
            hA[2] = (_Float16)acc[ct][2]; hA[3] = (_Float16)acc[ct][3];
            f32x4 o4 = __builtin_amdgcn_mfma_f32_16x16x16f16(hA, attf, z4, 0, 0, 0);
#pragma unroll
            for (int r = 0; r < 4; ++r) {
                float u = o4[r];
                o4[r] = u > 0.f ? u : (__expf(u) - 1.f);   // elu
            }
            dq[ct] = o4;
        }

        // ---- direct burst stores: 8 consecutive dwordx4; ct pairs (0,1),(2,3),...
        // cover each 128B line back-to-back -> L2 merges halves, no RMW fetch.
        {
            float* const orow = out + (size_t)b * 1920 + l15 * 128 + lq * 4;
            if (vrow) {
#pragma unroll
                for (int ct = 0; ct < 8; ++ct)
                    *(f32x4*)(orow + ct * 16) = dq[ct];
            }
        }
    }
}

extern "C" void kernel_launch(void* const* d_in, const int* in_sizes, int n_in,
                              void* d_out, int out_size, void* d_ws, size_t ws_size,
                              hipStream_t stream) {
    const float* x     = (const float*)d_in[0];
    const int*   adj   = (const int*)d_in[1];
    const float* W     = (const float*)d_in[2];
    const float* a_src = (const float*)d_in[3];
    const float* a_dst = (const float*)d_in[4];
    float* out = (float*)d_out;

    unsigned short* wt = (unsigned short*)d_ws;
    float* wa = (float*)((char*)d_ws + 32768);

    int B = in_sizes[0] / (15 * 128);
    int nblk = 2048;                            // 4 iters/wave at B=32768

    gat_pre<<<9, 256, 0, stream>>>(W, a_src, a_dst, wt, wa);
    gat_main<<<nblk, 256, 0, stream>>>(x, adj, wt, wa, out, B);
}